// Round 6
// baseline (218.984 us; speedup 1.0000x reference)
//
#include <hip/hip_runtime.h>
#include <math.h>

#define B_NUM 4
#define S_LEN 2048
#define D_DIM 1024
#define H_NUM 16
#define W_DIM 64

typedef float4 f4;
typedef _Float16 f16;
typedef f16 f16x8 __attribute__((ext_vector_type(8)));
typedef f16 f16x4 __attribute__((ext_vector_type(4)));
typedef float floatx4 __attribute__((ext_vector_type(4)));

#define GLOAD_LDS16(gp, lp)                                                     \
    __builtin_amdgcn_global_load_lds(                                           \
        (const __attribute__((address_space(1))) void*)(gp),                    \
        (__attribute__((address_space(3))) void*)(lp), 16, 0, 0)

// ---------------------------------------------------------------------------
// Fused pre-pass: one launch does all three independent jobs.
//   blocks [0,4)        : per-batch mask compaction (prefix-sum -> fwdmap/cnt)
//   blocks [4,772)      : W fp32 -> W^T f16 (64x64 tiles, 3 matrices)
//   blocks [772,8964)   : x fp32 -> f16 cast
// Masked keys contribute exp(-10000)==0 -> skipping them is exact.
// ---------------------------------------------------------------------------
#define TR_BLOCKS   768          // 16 x 16 x 3
#define CAST_BLOCKS 8192         // B*S*D / 1024

__global__ __launch_bounds__(256) void prep_kernel(
    const int* __restrict__ mask, short* __restrict__ fwdmap,
    int* __restrict__ cnt,
    const float* __restrict__ Wq, const float* __restrict__ Wk,
    const float* __restrict__ Wv, f16* __restrict__ wt16,
    const float* __restrict__ x, f16* __restrict__ x16)
{
    __shared__ __align__(16) char smraw[64 * 68 * 4];
    const int bx  = blockIdx.x;
    const int tid = threadIdx.x;

    if (bx < 4) {
        // ---- mask compaction ----
        int* sc = (int*)smraw;
        const int b  = bx;
        const int t0 = tid * 8;
#pragma unroll
        for (int j = 0; j < 8; ++j) fwdmap[b * S_LEN + t0 + j] = 0;  // pad default
        int kept[8], c = 0;
#pragma unroll
        for (int j = 0; j < 8; ++j) {
            kept[j] = (mask[b * S_LEN + t0 + j] == 0);
            c += kept[j];
        }
        sc[tid] = c;
        __syncthreads();
        for (int off = 1; off < 256; off <<= 1) {
            int add = (tid >= off) ? sc[tid - off] : 0;
            __syncthreads();
            sc[tid] += add;
            __syncthreads();
        }
        int base = sc[tid] - c;
#pragma unroll
        for (int j = 0; j < 8; ++j)
            if (kept[j]) fwdmap[b * S_LEN + (base++)] = (short)(t0 + j);
        if (tid == 255) {
            cnt[b * 4 + 0] = sc[255];
            cnt[b * 4 + 1] = (sc[255] + 63) & ~63;
            cnt[b * 4 + 2] = (sc[255] + 127) & ~127;
            cnt[b * 4 + 3] = (sc[255] + 255) & ~255;
        }
    } else if (bx < 4 + TR_BLOCKS) {
        // ---- W transpose + cast ----
        float (*ts)[68] = (float(*)[68])smraw;
        const int idx = bx - 4;
        const int k0 = (idx & 15) * 64;
        const int n0 = ((idx >> 4) & 15) * 64;
        const int z  = idx >> 8;
        const float* Wsel = (z == 0) ? Wq : (z == 1) ? Wk : Wv;
        f16* outp = wt16 + (size_t)z * D_DIM * D_DIM;

        const int r  = tid >> 4;
        const int c4 = (tid & 15) * 4;
#pragma unroll
        for (int i = 0; i < 4; ++i) {
            f4 t = *(const f4*)&Wsel[(size_t)(k0 + r + i * 16) * D_DIM + n0 + c4];
            *(f4*)&ts[r + i * 16][c4] = t;
        }
        __syncthreads();
#pragma unroll
        for (int i = 0; i < 4; ++i) {
            int id2 = tid + i * 256;
            int nl = id2 >> 4;
            int k4 = (id2 & 15) * 4;
            f16x4 o;
#pragma unroll
            for (int j = 0; j < 4; ++j) o[j] = (f16)ts[k4 + j][nl];
            *(f16x4*)&outp[(size_t)(n0 + nl) * D_DIM + k0 + k4] = o;
        }
    } else {
        // ---- x -> f16 cast ----
        const size_t i = (size_t)(bx - 4 - TR_BLOCKS) * 256 + tid;
        f4 t = *(const f4*)&x[i * 4];
        f16x4 o;
        o[0] = (f16)t.x; o[1] = (f16)t.y; o[2] = (f16)t.z; o[3] = (f16)t.w;
        *(f16x4*)&x16[i * 4] = o;
    }
}

// ---------------------------------------------------------------------------
// QKV GEMM, f16 MFMA, BK=64, XOR-swizzled LDS (measured 0 bank conflicts).
// 2-phase double-buffer (round 5: neutral on time vs round 0, VALUBusy
// 24->10 -- kept; this tile size's pipeline depth is closed, see notes).
//   Q -> (B,H,S,W) * 0.125 ; K -> (B,H,jc,W) ; V -> (B,H,W,jc)
// ---------------------------------------------------------------------------
#define QSTAGE(BUF, K0) do {                                                    \
    _Pragma("unroll") for (int it_ = 0; it_ < 4; ++it_) {                       \
        int chunk_ = wid * 4 + it_;                                             \
        GLOAD_LDS16(&x16[(size_t)arows[it_] * D_DIM + (K0) + scw],              \
                    &As[BUF][chunk_ * 512]);                                    \
        GLOAD_LDS16(&Bg[(size_t)(chunk_ * 8 + srow) * D_DIM + (K0) + scw],      \
                    &Bs[BUF][chunk_ * 512]);                                    \
    } } while (0)

#define QCOMPUTE(BUF) do {                                                      \
    _Pragma("unroll") for (int kh_ = 0; kh_ < 2; ++kh_) {                       \
        const int csw_ = ((kh_ * 4 + quad) ^ (lx & 7)) * 8;                     \
        f16x8 af_[4], bf_[4];                                                   \
        _Pragma("unroll") for (int tm_ = 0; tm_ < 4; ++tm_)                     \
            af_[tm_] = *(const f16x8*)&As[BUF][(wm * 64 + tm_ * 16 + lx) * 64 + csw_]; \
        _Pragma("unroll") for (int tn_ = 0; tn_ < 4; ++tn_)                     \
            bf_[tn_] = *(const f16x8*)&Bs[BUF][(wn * 64 + tn_ * 16 + lx) * 64 + csw_]; \
        _Pragma("unroll") for (int tm_ = 0; tm_ < 4; ++tm_)                     \
        _Pragma("unroll") for (int tn_ = 0; tn_ < 4; ++tn_)                     \
            acc[tm_][tn_] = __builtin_amdgcn_mfma_f32_16x16x32_f16(             \
                af_[tm_], bf_[tn_], acc[tm_][tn_], 0, 0, 0);                    \
    } } while (0)

#define QVM0BAR() do {                                                          \
    asm volatile("s_waitcnt vmcnt(0)" ::: "memory");                            \
    __builtin_amdgcn_s_barrier();                                               \
    } while (0)

__global__ __launch_bounds__(256) void qkv_mfma_kernel(
    const f16* __restrict__ x16, const f16* __restrict__ wt16,
    const float* __restrict__ bq, const float* __restrict__ bk,
    const float* __restrict__ bv, const short* __restrict__ fwdmap,
    const int* __restrict__ cnt,
    f16* __restrict__ Qo, f16* __restrict__ Ko, f16* __restrict__ Vo)
{
    __shared__ f16 As[2][128 * 64];
    __shared__ f16 Bs[2][128 * 64];

    const int tid  = threadIdx.x;
    const int lane = tid & 63;
    const int wid  = tid >> 6;
    const int lx   = lane & 15;
    const int quad = lane >> 4;
    const int wm   = wid >> 1;
    const int wn   = wid & 1;

    const int r0    = blockIdx.y * 128;
    const int nt    = blockIdx.x;
    const int midx  = nt >> 3;
    const int c0    = (nt & 7) * 128;
    const int bB    = r0 >> 11;               // batch (tiles never straddle)
    const int r0loc = r0 & (S_LEN - 1);

    if (midx > 0 && r0loc >= cnt[bB * 4 + 2]) return;   // block-uniform exit

    const f16* Bg = wt16 + (size_t)midx * D_DIM * D_DIM + (size_t)c0 * D_DIM;

    const int srow = lane >> 3;               // 0..7 within 8-row chunk
    const int scw  = ((lane & 7) ^ srow) * 8; // swizzled source k-chunk

    // A-row (global, batch-absolute) for each of this wave's 4 chunks
    int arows[4];
#pragma unroll
    for (int it = 0; it < 4; ++it) {
        int rl = (wid * 4 + it) * 8 + srow;   // 0..127 within tile
        arows[it] = (midx == 0)
            ? (r0 + rl)
            : (bB * S_LEN + (int)fwdmap[bB * S_LEN + r0loc + rl]);
    }

    floatx4 acc[4][4];
#pragma unroll
    for (int a = 0; a < 4; ++a)
#pragma unroll
        for (int b = 0; b < 4; ++b) { acc[a][b][0]=0.f; acc[a][b][1]=0.f; acc[a][b][2]=0.f; acc[a][b][3]=0.f; }

    // prologue: stage tile 0, wait, sync
    QSTAGE(0, 0);
    QVM0BAR();

    // steady state: stage t+1 under compute t
#pragma unroll 2
    for (int t = 0; t < 14; t += 2) {
        QSTAGE(1, (t + 1) * 64);
        QCOMPUTE(0);
        QVM0BAR();
        QSTAGE(0, (t + 2) * 64);
        QCOMPUTE(1);
        QVM0BAR();
    }
    // tiles 14, 15
    QSTAGE(1, 15 * 64);
    QCOMPUTE(0);
    QVM0BAR();
    QCOMPUTE(1);

    const float* bp = (midx == 0) ? bq : (midx == 1) ? bk : bv;
    float bias[4];
#pragma unroll
    for (int tn = 0; tn < 4; ++tn)
        bias[tn] = bp[c0 + wn * 64 + tn * 16 + lx];

    if (midx == 0) {
#pragma unroll
        for (int tm = 0; tm < 4; ++tm) {
            int s = r0loc + wm * 64 + tm * 16 + quad * 4;
#pragma unroll
            for (int tn = 0; tn < 4; ++tn) {
                int gc = c0 + wn * 64 + tn * 16 + lx;
                int h = gc >> 6, w = gc & 63;
                size_t base = (((size_t)(bB * H_NUM + h)) * S_LEN + s) * W_DIM + w;
#pragma unroll
                for (int rr = 0; rr < 4; ++rr)
                    Qo[base + (size_t)rr * W_DIM] =
                        (f16)((acc[tm][tn][rr] + bias[tn]) * 0.125f);
            }
        }
    } else if (midx == 1) {
#pragma unroll
        for (int tm = 0; tm < 4; ++tm) {
            int jc = r0loc + wm * 64 + tm * 16 + quad * 4;
#pragma unroll
            for (int tn = 0; tn < 4; ++tn) {
                int gc = c0 + wn * 64 + tn * 16 + lx;
                int h = gc >> 6, w = gc & 63;
                size_t base = (((size_t)(bB * H_NUM + h)) * S_LEN + jc) * W_DIM + w;
#pragma unroll
                for (int rr = 0; rr < 4; ++rr)
                    Ko[base + (size_t)rr * W_DIM] = (f16)(acc[tm][tn][rr] + bias[tn]);
            }
        }
    } else {
#pragma unroll
        for (int tm = 0; tm < 4; ++tm) {
            int jc = r0loc + wm * 64 + tm * 16 + quad * 4;
#pragma unroll
            for (int tn = 0; tn < 4; ++tn) {
                int gc = c0 + wn * 64 + tn * 16 + lx;
                int h = gc >> 6, w = gc & 63;
                f16x4 v;
#pragma unroll
                for (int rr = 0; rr < 4; ++rr) v[rr] = (f16)(acc[tm][tn][rr] + bias[tn]);
                *(f16x4*)&Vo[(((size_t)(bB * H_NUM + h)) * W_DIM + w) * S_LEN + jc] = v;
            }
        }
    }
}

// ---------------------------------------------------------------------------
// Flash attention over COMPACTED keys, S^T formulation, 2 q-tiles per wave.
// ROUND 6: conflict-free LDS + PV MFMA halving via K-row permutation.
//  * Old layout (LSTR=72, 144B rows) had 4-way bank conflicts on K b128 and
//    V b64 reads (measured 6.4M conflict cycles). New: [64][64] rows + the
//    qkv-proven 16B-chunk XOR swizzle (chunk ^ (row&7)) -- measured 0 there.
//  * K rows are stored PERMUTED within each 64-key tile: LDS row
//    rho = n*16 + quad*4 + r holds key (n>>1)*32 + quad*8 + (n&1)*4 + r
//    (bijective; k-sum order is irrelevant). Consequence: a lane's QK^T
//    outputs for block pair (2m, 2m+1) are keys quad*8..+7 -- contiguous --
//    so P packs IN-REGISTER (no shuffles) into a f16x8 B-operand and PV
//    runs 16x16x32 MFMA: 16 instead of 32 per k-tile, same FLOP. V stays in
//    original key order (exactly what the A-operand k-slots need).
//  * Tail mask uses the permuted key id. Everything else (staging schedule,
//    __expf, epilogue) is the proven round-0 code.
// ---------------------------------------------------------------------------
__global__ __launch_bounds__(256) void attn_kernel(
    const f16* __restrict__ Q, const f16* __restrict__ Kc,
    const f16* __restrict__ Vct, const int* __restrict__ cnt,
    float* __restrict__ out)
{
    __shared__ f16 Ks[64][64];      // [perm key][k]   swizzled 16B chunks
    __shared__ f16 Vs[64][64];      // [w][key]        swizzled 16B chunks

    const int tid  = threadIdx.x;
    const int lane = tid & 63;
    const int wid  = tid >> 6;
    const int lx   = lane & 15;
    const int quad = lane >> 4;
    const int qt = blockIdx.x, h = blockIdx.y, bb = blockIdx.z;

    const int count = cnt[bb * 4 + 0];
    const int scp   = cnt[bb * 4 + 1];

    const size_t hoff = ((size_t)(bb * H_NUM + h)) * S_LEN * W_DIM;
    const f16* Qg = Q + hoff + (size_t)qt * 128 * W_DIM;
    const f16* Kg = Kc + hoff;
    const f16* Vg = Vct + hoff;

    f16x8 qb[2][2];
#pragma unroll
    for (int u = 0; u < 2; ++u) {
        int qrow = u * 64 + wid * 16 + lx;
        qb[u][0] = *(const f16x8*)&Qg[(size_t)qrow * W_DIM + quad * 8];
        qb[u][1] = *(const f16x8*)&Qg[(size_t)qrow * W_DIM + 32 + quad * 8];
    }

    floatx4 o[2][4];
    float lsum[2] = {0.f, 0.f};
#pragma unroll
    for (int u = 0; u < 2; ++u)
#pragma unroll
        for (int wb = 0; wb < 4; ++wb) { o[u][wb][0]=0.f; o[u][wb][1]=0.f; o[u][wb][2]=0.f; o[u][wb][3]=0.f; }

    const int swz = lx & 7;                    // read-side de-swizzle key

    for (int k0 = 0; k0 < scp; k0 += 64) {
        __syncthreads();
#pragma unroll
        for (int it = 0; it < 2; ++it) {
            int idx = tid + it * 256;
            int row = idx >> 3;                // 0..63
            int ci  = idx & 7;                 // 16B chunk 0..7
            int cs  = (ci ^ (row & 7)) * 8;    // swizzled chunk offset (f16)
            // K-row permutation: row -> key  (m=row>>5, qd=(row>>2)&3,
            // hh=(row>>4)&1, rr=row&3; key = m*32 + qd*8 + hh*4 + rr)
            int key = ((row >> 5) << 5) | (((row >> 2) & 3) << 3)
                    | (((row >> 4) & 1) << 2) | (row & 3);
            *(f16x8*)&Ks[row][cs] = *(const f16x8*)&Kg[(size_t)(k0 + key) * W_DIM + ci * 8];
            *(f16x8*)&Vs[row][cs] = *(const f16x8*)&Vg[(size_t)row * S_LEN + k0 + ci * 8];
        }
        __syncthreads();

        const bool tail = (k0 + 64 > count);

        f16x8 pb8[2][2];                       // [u][m]: keys m*32+quad*8 .. +8
#pragma unroll
        for (int n = 0; n < 4; ++n) {
            f16x8 ka0 = *(const f16x8*)&Ks[n * 16 + lx][((0 + quad) ^ swz) * 8];
            f16x8 ka1 = *(const f16x8*)&Ks[n * 16 + lx][((4 + quad) ^ swz) * 8];
            // permuted key base for this lane's 4 outputs of block n
            const int kb = k0 + ((n >> 1) << 5) + (quad << 3) + ((n & 1) << 2);
#pragma unroll
            for (int u = 0; u < 2; ++u) {
                floatx4 s; s[0]=0.f; s[1]=0.f; s[2]=0.f; s[3]=0.f;
                s = __builtin_amdgcn_mfma_f32_16x16x32_f16(ka0, qb[u][0], s, 0, 0, 0);
                s = __builtin_amdgcn_mfma_f32_16x16x32_f16(ka1, qb[u][1], s, 0, 0, 0);
                float p[4], ls = 0.f;
                if (tail) {
#pragma unroll
                    for (int r = 0; r < 4; ++r) {
                        float sv = (kb + r < count) ? s[r] : -1.0e4f;
                        p[r] = __expf(sv); ls += p[r];
                    }
                } else {
#pragma unroll
                    for (int r = 0; r < 4; ++r) { p[r] = __expf(s[r]); ls += p[r]; }
                }
                lsum[u] += ls;
#pragma unroll
                for (int r = 0; r < 4; ++r)
                    pb8[u][n >> 1][(n & 1) * 4 + r] = (f16)p[r];
            }
        }

#pragma unroll
        for (int wb = 0; wb < 4; ++wb) {
#pragma unroll
            for (int m = 0; m < 2; ++m) {
                f16x8 va = *(const f16x8*)&Vs[wb * 16 + lx][((m * 4 + quad) ^ swz) * 8];
#pragma unroll
                for (int u = 0; u < 2; ++u)
                    o[u][wb] = __builtin_amdgcn_mfma_f32_16x16x32_f16(
                        va, pb8[u][m], o[u][wb], 0, 0, 0);
            }
        }
    }

#pragma unroll
    for (int u = 0; u < 2; ++u) {
        float ls = lsum[u];
        ls += __shfl_xor(ls, 16);
        ls += __shfl_xor(ls, 32);
        const float rl = 1.0f / ls;
        const int q = qt * 128 + u * 64 + wid * 16 + lx;
        const size_t base = ((size_t)bb * S_LEN + q) * D_DIM + h * W_DIM;
#pragma unroll
        for (int wb = 0; wb < 4; ++wb) {
            f4 r;
            r.x = o[u][wb][0] * rl;
            r.y = o[u][wb][1] * rl;
            r.z = o[u][wb][2] * rl;
            r.w = o[u][wb][3] * rl;
            *(f4*)&out[base + wb * 16 + quad * 4] = r;
        }
    }
}

// ---------------------------------------------------------------------------
extern "C" void kernel_launch(void* const* d_in, const int* in_sizes, int n_in,
                              void* d_out, int out_size, void* d_ws, size_t ws_size,
                              hipStream_t stream)
{
    const float* x    = (const float*)d_in[0];
    const float* Wq   = (const float*)d_in[1];
    const float* bq   = (const float*)d_in[2];
    const float* Wk   = (const float*)d_in[3];
    const float* bk   = (const float*)d_in[4];
    const float* Wv   = (const float*)d_in[5];
    const float* bv   = (const float*)d_in[6];
    const int*   mask = (const int*)d_in[7];
    float* out = (float*)d_out;

    const size_t per = (size_t)B_NUM * H_NUM * S_LEN * W_DIM;  // 8,388,608
    f16*   Q      = (f16*)d_ws;
    f16*   Kc     = Q + per;
    f16*   Vct    = Kc + per;
    f16*   x16    = Vct + per;
    f16*   wt16   = x16 + (size_t)(B_NUM * S_LEN) * D_DIM;
    int*   cnt    = (int*)(wt16 + (size_t)3 * D_DIM * D_DIM);
    short* fwdmap = (short*)(cnt + 4 * B_NUM);

    prep_kernel<<<4 + TR_BLOCKS + CAST_BLOCKS, 256, 0, stream>>>(
        mask, fwdmap, cnt, Wq, Wk, Wv, wt16, x, x16);
    qkv_mfma_kernel<<<dim3(24, 64), 256, 0, stream>>>(
        x16, wt16, bq, bk, bv, fwdmap, cnt, Q, Kc, Vct);
    attn_kernel<<<dim3(S_LEN / 128, H_NUM, B_NUM), 256, 0, stream>>>(
        Q, Kc, Vct, cnt, out);
}

// Round 7
// 218.666 us; speedup vs baseline: 1.0015x; 1.0015x over previous
//
#include <hip/hip_runtime.h>
#include <math.h>

#define B_NUM 4
#define S_LEN 2048
#define D_DIM 1024
#define H_NUM 16
#define W_DIM 64

typedef float4 f4;
typedef _Float16 f16;
typedef f16 f16x8 __attribute__((ext_vector_type(8)));
typedef f16 f16x4 __attribute__((ext_vector_type(4)));
typedef float floatx4 __attribute__((ext_vector_type(4)));

#define GLOAD_LDS16(gp, lp)                                                     \
    __builtin_amdgcn_global_load_lds(                                           \
        (const __attribute__((address_space(1))) void*)(gp),                    \
        (__attribute__((address_space(3))) void*)(lp), 16, 0, 0)

// ---------------------------------------------------------------------------
// Fused pre-pass: one launch does all three independent jobs.
//   blocks [0,4)        : per-batch mask compaction (prefix-sum -> fwdmap/cnt)
//   blocks [4,772)      : W fp32 -> W^T f16 (64x64 tiles, 3 matrices)
//   blocks [772,8964)   : x fp32 -> f16 cast
// Masked keys contribute exp(-10000)==0 -> skipping them is exact.
// ---------------------------------------------------------------------------
#define TR_BLOCKS   768          // 16 x 16 x 3
#define CAST_BLOCKS 8192         // B*S*D / 1024

__global__ __launch_bounds__(256) void prep_kernel(
    const int* __restrict__ mask, short* __restrict__ fwdmap,
    int* __restrict__ cnt,
    const float* __restrict__ Wq, const float* __restrict__ Wk,
    const float* __restrict__ Wv, f16* __restrict__ wt16,
    const float* __restrict__ x, f16* __restrict__ x16)
{
    __shared__ __align__(16) char smraw[64 * 68 * 4];
    const int bx  = blockIdx.x;
    const int tid = threadIdx.x;

    if (bx < 4) {
        // ---- mask compaction ----
        int* sc = (int*)smraw;
        const int b  = bx;
        const int t0 = tid * 8;
#pragma unroll
        for (int j = 0; j < 8; ++j) fwdmap[b * S_LEN + t0 + j] = 0;  // pad default
        int kept[8], c = 0;
#pragma unroll
        for (int j = 0; j < 8; ++j) {
            kept[j] = (mask[b * S_LEN + t0 + j] == 0);
            c += kept[j];
        }
        sc[tid] = c;
        __syncthreads();
        for (int off = 1; off < 256; off <<= 1) {
            int add = (tid >= off) ? sc[tid - off] : 0;
            __syncthreads();
            sc[tid] += add;
            __syncthreads();
        }
        int base = sc[tid] - c;
#pragma unroll
        for (int j = 0; j < 8; ++j)
            if (kept[j]) fwdmap[b * S_LEN + (base++)] = (short)(t0 + j);
        if (tid == 255) {
            cnt[b * 4 + 0] = sc[255];
            cnt[b * 4 + 1] = (sc[255] + 63) & ~63;
            cnt[b * 4 + 2] = (sc[255] + 127) & ~127;
            cnt[b * 4 + 3] = (sc[255] + 255) & ~255;
        }
    } else if (bx < 4 + TR_BLOCKS) {
        // ---- W transpose + cast ----
        float (*ts)[68] = (float(*)[68])smraw;
        const int idx = bx - 4;
        const int k0 = (idx & 15) * 64;
        const int n0 = ((idx >> 4) & 15) * 64;
        const int z  = idx >> 8;
        const float* Wsel = (z == 0) ? Wq : (z == 1) ? Wk : Wv;
        f16* outp = wt16 + (size_t)z * D_DIM * D_DIM;

        const int r  = tid >> 4;
        const int c4 = (tid & 15) * 4;
#pragma unroll
        for (int i = 0; i < 4; ++i) {
            f4 t = *(const f4*)&Wsel[(size_t)(k0 + r + i * 16) * D_DIM + n0 + c4];
            *(f4*)&ts[r + i * 16][c4] = t;
        }
        __syncthreads();
#pragma unroll
        for (int i = 0; i < 4; ++i) {
            int id2 = tid + i * 256;
            int nl = id2 >> 4;
            int k4 = (id2 & 15) * 4;
            f16x4 o;
#pragma unroll
            for (int j = 0; j < 4; ++j) o[j] = (f16)ts[k4 + j][nl];
            *(f16x4*)&outp[(size_t)(n0 + nl) * D_DIM + k0 + k4] = o;
        }
    } else {
        // ---- x -> f16 cast ----
        const size_t i = (size_t)(bx - 4 - TR_BLOCKS) * 256 + tid;
        f4 t = *(const f4*)&x[i * 4];
        f16x4 o;
        o[0] = (f16)t.x; o[1] = (f16)t.y; o[2] = (f16)t.z; o[3] = (f16)t.w;
        *(f16x4*)&x16[i * 4] = o;
    }
}

// ---------------------------------------------------------------------------
// QKV GEMM, f16 MFMA, BK=64, XOR-swizzled LDS (measured 0 bank conflicts).
// 2-phase double-buffer (round 5). Unchanged.
//   Q -> (B,H,S,W) * 0.125 ; K -> (B,H,jc,W) ; V -> (B,H,W,jc)
// ---------------------------------------------------------------------------
#define QSTAGE(BUF, K0) do {                                                    \
    _Pragma("unroll") for (int it_ = 0; it_ < 4; ++it_) {                       \
        int chunk_ = wid * 4 + it_;                                             \
        GLOAD_LDS16(&x16[(size_t)arows[it_] * D_DIM + (K0) + scw],              \
                    &As[BUF][chunk_ * 512]);                                    \
        GLOAD_LDS16(&Bg[(size_t)(chunk_ * 8 + srow) * D_DIM + (K0) + scw],      \
                    &Bs[BUF][chunk_ * 512]);                                    \
    } } while (0)

#define QCOMPUTE(BUF) do {                                                      \
    _Pragma("unroll") for (int kh_ = 0; kh_ < 2; ++kh_) {                       \
        const int csw_ = ((kh_ * 4 + quad) ^ (lx & 7)) * 8;                     \
        f16x8 af_[4], bf_[4];                                                   \
        _Pragma("unroll") for (int tm_ = 0; tm_ < 4; ++tm_)                     \
            af_[tm_] = *(const f16x8*)&As[BUF][(wm * 64 + tm_ * 16 + lx) * 64 + csw_]; \
        _Pragma("unroll") for (int tn_ = 0; tn_ < 4; ++tn_)                     \
            bf_[tn_] = *(const f16x8*)&Bs[BUF][(wn * 64 + tn_ * 16 + lx) * 64 + csw_]; \
        _Pragma("unroll") for (int tm_ = 0; tm_ < 4; ++tm_)                     \
        _Pragma("unroll") for (int tn_ = 0; tn_ < 4; ++tn_)                     \
            acc[tm_][tn_] = __builtin_amdgcn_mfma_f32_16x16x32_f16(             \
                af_[tm_], bf_[tn_], acc[tm_][tn_], 0, 0, 0);                    \
    } } while (0)

#define QVM0BAR() do {                                                          \
    asm volatile("s_waitcnt vmcnt(0)" ::: "memory");                            \
    __builtin_amdgcn_s_barrier();                                               \
    } while (0)

__global__ __launch_bounds__(256) void qkv_mfma_kernel(
    const f16* __restrict__ x16, const f16* __restrict__ wt16,
    const float* __restrict__ bq, const float* __restrict__ bk,
    const float* __restrict__ bv, const short* __restrict__ fwdmap,
    const int* __restrict__ cnt,
    f16* __restrict__ Qo, f16* __restrict__ Ko, f16* __restrict__ Vo)
{
    __shared__ f16 As[2][128 * 64];
    __shared__ f16 Bs[2][128 * 64];

    const int tid  = threadIdx.x;
    const int lane = tid & 63;
    const int wid  = tid >> 6;
    const int lx   = lane & 15;
    const int quad = lane >> 4;
    const int wm   = wid >> 1;
    const int wn   = wid & 1;

    const int r0    = blockIdx.y * 128;
    const int nt    = blockIdx.x;
    const int midx  = nt >> 3;
    const int c0    = (nt & 7) * 128;
    const int bB    = r0 >> 11;               // batch (tiles never straddle)
    const int r0loc = r0 & (S_LEN - 1);

    if (midx > 0 && r0loc >= cnt[bB * 4 + 2]) return;   // block-uniform exit

    const f16* Bg = wt16 + (size_t)midx * D_DIM * D_DIM + (size_t)c0 * D_DIM;

    const int srow = lane >> 3;               // 0..7 within 8-row chunk
    const int scw  = ((lane & 7) ^ srow) * 8; // swizzled source k-chunk

    // A-row (global, batch-absolute) for each of this wave's 4 chunks
    int arows[4];
#pragma unroll
    for (int it = 0; it < 4; ++it) {
        int rl = (wid * 4 + it) * 8 + srow;   // 0..127 within tile
        arows[it] = (midx == 0)
            ? (r0 + rl)
            : (bB * S_LEN + (int)fwdmap[bB * S_LEN + r0loc + rl]);
    }

    floatx4 acc[4][4];
#pragma unroll
    for (int a = 0; a < 4; ++a)
#pragma unroll
        for (int b = 0; b < 4; ++b) { acc[a][b][0]=0.f; acc[a][b][1]=0.f; acc[a][b][2]=0.f; acc[a][b][3]=0.f; }

    // prologue: stage tile 0, wait, sync
    QSTAGE(0, 0);
    QVM0BAR();

    // steady state: stage t+1 under compute t
#pragma unroll 2
    for (int t = 0; t < 14; t += 2) {
        QSTAGE(1, (t + 1) * 64);
        QCOMPUTE(0);
        QVM0BAR();
        QSTAGE(0, (t + 2) * 64);
        QCOMPUTE(1);
        QVM0BAR();
    }
    // tiles 14, 15
    QSTAGE(1, 15 * 64);
    QCOMPUTE(0);
    QVM0BAR();
    QCOMPUTE(1);

    const float* bp = (midx == 0) ? bq : (midx == 1) ? bk : bv;
    float bias[4];
#pragma unroll
    for (int tn = 0; tn < 4; ++tn)
        bias[tn] = bp[c0 + wn * 64 + tn * 16 + lx];

    if (midx == 0) {
#pragma unroll
        for (int tm = 0; tm < 4; ++tm) {
            int s = r0loc + wm * 64 + tm * 16 + quad * 4;
#pragma unroll
            for (int tn = 0; tn < 4; ++tn) {
                int gc = c0 + wn * 64 + tn * 16 + lx;
                int h = gc >> 6, w = gc & 63;
                size_t base = (((size_t)(bB * H_NUM + h)) * S_LEN + s) * W_DIM + w;
#pragma unroll
                for (int rr = 0; rr < 4; ++rr)
                    Qo[base + (size_t)rr * W_DIM] =
                        (f16)((acc[tm][tn][rr] + bias[tn]) * 0.125f);
            }
        }
    } else if (midx == 1) {
#pragma unroll
        for (int tm = 0; tm < 4; ++tm) {
            int jc = r0loc + wm * 64 + tm * 16 + quad * 4;
#pragma unroll
            for (int tn = 0; tn < 4; ++tn) {
                int gc = c0 + wn * 64 + tn * 16 + lx;
                int h = gc >> 6, w = gc & 63;
                size_t base = (((size_t)(bB * H_NUM + h)) * S_LEN + jc) * W_DIM + w;
#pragma unroll
                for (int rr = 0; rr < 4; ++rr)
                    Ko[base + (size_t)rr * W_DIM] = (f16)(acc[tm][tn][rr] + bias[tn]);
            }
        }
    } else {
#pragma unroll
        for (int tm = 0; tm < 4; ++tm) {
            int jc = r0loc + wm * 64 + tm * 16 + quad * 4;
#pragma unroll
            for (int tn = 0; tn < 4; ++tn) {
                int gc = c0 + wn * 64 + tn * 16 + lx;
                int h = gc >> 6, w = gc & 63;
                f16x4 v;
#pragma unroll
                for (int rr = 0; rr < 4; ++rr) v[rr] = (f16)(acc[tm][tn][rr] + bias[tn]);
                *(f16x4*)&Vo[(((size_t)(bB * H_NUM + h)) * W_DIM + w) * S_LEN + jc] = v;
            }
        }
    }
}

// ---------------------------------------------------------------------------
// Flash attention over COMPACTED keys, S^T formulation, 2 q-tiles per wave.
// ROUND 7: staging mechanism ported from the round-5-proven qkv loop.
//  * Double-buffered Ks/Vs [2][64][64] (32 KB total -> up to 5 blocks/CU
//    resident vs ~2 before).
//  * global_load_lds direct-to-LDS staging: linear lane-ordered dest (HW
//    requirement), per-lane SOURCE address carries both the K-row
//    permutation and the XOR chunk swizzle (rule: swizzle source + read,
//    dest linear; XOR is an involution so the algebra matches the old
//    reg-staged writes bit-exactly).
//  * Loop = {stage t+1 into buf^1; compute buf t; vmcnt(0); s_barrier} --
//    ONE barrier per tile, no lgkm staging drain, no reg round-trip; the
//    4 loads/thread hide under ~700+ cyc of compute (> L2 latency).
//    Buffer safety identical to qkv: ds_reads of the overwritten buffer
//    retired (MFMA data-dep) before the barrier preceding the stage.
//  * Model note: derived-counter absolutes are inflated ~4x on gfx950
//    (gfx94x formula fallback); arithmetic says ~70-80% of the old attn
//    k-tile was staging stall -- this is the mechanism-level fix.
//  Compute body (QK^T, permuted-key packing, 16x16x32 PV, __expf) is the
//  round-6 code, unchanged.
// ---------------------------------------------------------------------------
#define ASTAGE(BUF, K0) do {                                                    \
    _Pragma("unroll") for (int it_ = 0; it_ < 2; ++it_) {                       \
        int idx_ = tid + it_ * 256;                                             \
        int row_ = idx_ >> 3, ci_ = idx_ & 7;                                   \
        int sc_  = (ci_ ^ (row_ & 7)) * 8;                                      \
        int key_ = ((row_ >> 5) << 5) | (((row_ >> 2) & 3) << 3)                \
                 | (((row_ >> 4) & 1) << 2) | (row_ & 3);                       \
        GLOAD_LDS16(&Kg[(size_t)((K0) + key_) * W_DIM + sc_],                   \
                    (f16*)Ks[BUF] + idx_ * 8);                                  \
        GLOAD_LDS16(&Vg[(size_t)row_ * S_LEN + (K0) + sc_],                     \
                    (f16*)Vs[BUF] + idx_ * 8);                                  \
    } } while (0)

#define ACOMPUTE(BUF, K0) do {                                                  \
    const bool tail_ = ((K0) + 64 > count);                                     \
    f16x8 pb8[2][2];                                                            \
    _Pragma("unroll") for (int n = 0; n < 4; ++n) {                             \
        f16x8 ka0 = *(const f16x8*)&Ks[BUF][n * 16 + lx][((0 + quad) ^ swz) * 8]; \
        f16x8 ka1 = *(const f16x8*)&Ks[BUF][n * 16 + lx][((4 + quad) ^ swz) * 8]; \
        const int kb = (K0) + ((n >> 1) << 5) + (quad << 3) + ((n & 1) << 2);   \
        _Pragma("unroll") for (int u = 0; u < 2; ++u) {                         \
            floatx4 s; s[0]=0.f; s[1]=0.f; s[2]=0.f; s[3]=0.f;                  \
            s = __builtin_amdgcn_mfma_f32_16x16x32_f16(ka0, qb[u][0], s, 0, 0, 0); \
            s = __builtin_amdgcn_mfma_f32_16x16x32_f16(ka1, qb[u][1], s, 0, 0, 0); \
            float p[4], ls = 0.f;                                               \
            if (tail_) {                                                        \
                _Pragma("unroll") for (int r = 0; r < 4; ++r) {                 \
                    float sv = (kb + r < count) ? s[r] : -1.0e4f;               \
                    p[r] = __expf(sv); ls += p[r];                              \
                }                                                               \
            } else {                                                            \
                _Pragma("unroll") for (int r = 0; r < 4; ++r) {                 \
                    p[r] = __expf(s[r]); ls += p[r]; }                          \
            }                                                                   \
            lsum[u] += ls;                                                      \
            _Pragma("unroll") for (int r = 0; r < 4; ++r)                       \
                pb8[u][n >> 1][(n & 1) * 4 + r] = (f16)p[r];                    \
        }                                                                       \
    }                                                                           \
    _Pragma("unroll") for (int wb = 0; wb < 4; ++wb) {                          \
        _Pragma("unroll") for (int m = 0; m < 2; ++m) {                         \
            f16x8 va = *(const f16x8*)&Vs[BUF][wb * 16 + lx][((m * 4 + quad) ^ swz) * 8]; \
            _Pragma("unroll") for (int u = 0; u < 2; ++u)                       \
                o[u][wb] = __builtin_amdgcn_mfma_f32_16x16x32_f16(              \
                    va, pb8[u][m], o[u][wb], 0, 0, 0);                          \
        }                                                                       \
    } } while (0)

__global__ __launch_bounds__(256) void attn_kernel(
    const f16* __restrict__ Q, const f16* __restrict__ Kc,
    const f16* __restrict__ Vct, const int* __restrict__ cnt,
    float* __restrict__ out)
{
    __shared__ f16 Ks[2][64][64];   // [buf][perm key][k]  swizzled 16B chunks
    __shared__ f16 Vs[2][64][64];   // [buf][w][key]       swizzled 16B chunks

    const int tid  = threadIdx.x;
    const int lane = tid & 63;
    const int wid  = tid >> 6;
    const int lx   = lane & 15;
    const int quad = lane >> 4;
    const int qt = blockIdx.x, h = blockIdx.y, bb = blockIdx.z;

    const int count = cnt[bb * 4 + 0];
    const int scp   = cnt[bb * 4 + 1];
    const int ntile = scp >> 6;

    const size_t hoff = ((size_t)(bb * H_NUM + h)) * S_LEN * W_DIM;
    const f16* Qg = Q + hoff + (size_t)qt * 128 * W_DIM;
    const f16* Kg = Kc + hoff;
    const f16* Vg = Vct + hoff;

    f16x8 qb[2][2];
#pragma unroll
    for (int u = 0; u < 2; ++u) {
        int qrow = u * 64 + wid * 16 + lx;
        qb[u][0] = *(const f16x8*)&Qg[(size_t)qrow * W_DIM + quad * 8];
        qb[u][1] = *(const f16x8*)&Qg[(size_t)qrow * W_DIM + 32 + quad * 8];
    }

    floatx4 o[2][4];
    float lsum[2] = {0.f, 0.f};
#pragma unroll
    for (int u = 0; u < 2; ++u)
#pragma unroll
        for (int wb = 0; wb < 4; ++wb) { o[u][wb][0]=0.f; o[u][wb][1]=0.f; o[u][wb][2]=0.f; o[u][wb][3]=0.f; }

    const int swz = lx & 7;                    // read-side de-swizzle key

    // prologue: stage tile 0, wait, sync
    ASTAGE(0, 0);
    asm volatile("s_waitcnt vmcnt(0)" ::: "memory");
    __builtin_amdgcn_s_barrier();

    // steady state: stage t+1 under compute t  (all guards block-uniform)
    for (int t = 0; t < ntile; t += 2) {
        if (t + 1 < ntile) ASTAGE(1, (t + 1) * 64);
        ACOMPUTE(0, t * 64);
        asm volatile("s_waitcnt vmcnt(0)" ::: "memory");
        __builtin_amdgcn_s_barrier();
        if (t + 1 < ntile) {
            if (t + 2 < ntile) ASTAGE(0, (t + 2) * 64);
            ACOMPUTE(1, (t + 1) * 64);
            asm volatile("s_waitcnt vmcnt(0)" ::: "memory");
            __builtin_amdgcn_s_barrier();
        }
    }

#pragma unroll
    for (int u = 0; u < 2; ++u) {
        float ls = lsum[u];
        ls += __shfl_xor(ls, 16);
        ls += __shfl_xor(ls, 32);
        const float rl = 1.0f / ls;
        const int q = qt * 128 + u * 64 + wid * 16 + lx;
        const size_t base = ((size_t)bb * S_LEN + q) * D_DIM + h * W_DIM;
#pragma unroll
        for (int wb = 0; wb < 4; ++wb) {
            f4 r;
            r.x = o[u][wb][0] * rl;
            r.y = o[u][wb][1] * rl;
            r.z = o[u][wb][2] * rl;
            r.w = o[u][wb][3] * rl;
            *(f4*)&out[base + wb * 16 + quad * 4] = r;
        }
    }
}

// ---------------------------------------------------------------------------
extern "C" void kernel_launch(void* const* d_in, const int* in_sizes, int n_in,
                              void* d_out, int out_size, void* d_ws, size_t ws_size,
                              hipStream_t stream)
{
    const float* x    = (const float*)d_in[0];
    const float* Wq   = (const float*)d_in[1];
    const float* bq   = (const float*)d_in[2];
    const float* Wk   = (const float*)d_in[3];
    const float* bk   = (const float*)d_in[4];
    const float* Wv   = (const float*)d_in[5];
    const float* bv   = (const float*)d_in[6];
    const int*   mask = (const int*)d_in[7];
    float* out = (float*)d_out;

    const size_t per = (size_t)B_NUM * H_NUM * S_LEN * W_DIM;  // 8,388,608
    f16*   Q      = (f16*)d_ws;
    f16*   Kc     = Q + per;
    f16*   Vct    = Kc + per;
    f16*   x16    = Vct + per;
    f16*   wt16   = x16 + (size_t)(B_NUM * S_LEN) * D_DIM;
    int*   cnt    = (int*)(wt16 + (size_t)3 * D_DIM * D_DIM);
    short* fwdmap = (short*)(cnt + 4 * B_NUM);

    prep_kernel<<<4 + TR_BLOCKS + CAST_BLOCKS, 256, 0, stream>>>(
        mask, fwdmap, cnt, Wq, Wk, Wv, wt16, x, x16);
    qkv_mfma_kernel<<<dim3(24, 64), 256, 0, stream>>>(
        x16, wt16, bq, bk, bv, fwdmap, cnt, Q, Kc, Vct);
    attn_kernel<<<dim3(S_LEN / 128, H_NUM, B_NUM), 256, 0, stream>>>(
        Q, Kc, Vct, cnt, out);
}

// Round 8
// 215.627 us; speedup vs baseline: 1.0156x; 1.0141x over previous
//
#include <hip/hip_runtime.h>
#include <math.h>

#define B_NUM 4
#define S_LEN 2048
#define D_DIM 1024
#define H_NUM 16
#define W_DIM 64

typedef float4 f4;
typedef _Float16 f16;
typedef f16 f16x8 __attribute__((ext_vector_type(8)));
typedef f16 f16x4 __attribute__((ext_vector_type(4)));
typedef float floatx4 __attribute__((ext_vector_type(4)));
typedef unsigned int u32;
typedef u32 u32x4 __attribute__((ext_vector_type(4)));

// Raw v_exp_f32 (2^x). Q is pre-scaled by 0.125*log2(e) in the qkv epilogue,
// so softmax needs no per-element multiply. Fallback keeps exact semantics
// (exp(x*ln2) == 2^x) at the cost of the mul we are trying to remove.
#if __has_builtin(__builtin_amdgcn_exp2f)
#define FEXP2(x) __builtin_amdgcn_exp2f(x)
#else
#define FEXP2(x) __expf((x) * 0.6931471805599453f)
#endif
#define QSCALE 0.18033688011f   /* 0.125 * log2(e) */

#define GLOAD_LDS16(gp, lp)                                                     \
    __builtin_amdgcn_global_load_lds(                                           \
        (const __attribute__((address_space(1))) void*)(gp),                    \
        (__attribute__((address_space(3))) void*)(lp), 16, 0, 0)

// ---------------------------------------------------------------------------
// Fused pre-pass: one launch does all three independent jobs.
//   blocks [0,4)        : per-batch mask compaction (prefix-sum -> fwdmap/cnt)
//   blocks [4,772)      : W fp32 -> W^T f16 (64x64 tiles, 3 matrices)
//   blocks [772,8964)   : x fp32 -> f16 cast
// Masked keys contribute exp(-10000)==0 -> skipping them is exact.
// ---------------------------------------------------------------------------
#define TR_BLOCKS   768          // 16 x 16 x 3
#define CAST_BLOCKS 8192         // B*S*D / 1024

__global__ __launch_bounds__(256) void prep_kernel(
    const int* __restrict__ mask, short* __restrict__ fwdmap,
    int* __restrict__ cnt,
    const float* __restrict__ Wq, const float* __restrict__ Wk,
    const float* __restrict__ Wv, f16* __restrict__ wt16,
    const float* __restrict__ x, f16* __restrict__ x16)
{
    __shared__ __align__(16) char smraw[64 * 68 * 4];
    const int bx  = blockIdx.x;
    const int tid = threadIdx.x;

    if (bx < 4) {
        // ---- mask compaction ----
        int* sc = (int*)smraw;
        const int b  = bx;
        const int t0 = tid * 8;
#pragma unroll
        for (int j = 0; j < 8; ++j) fwdmap[b * S_LEN + t0 + j] = 0;  // pad default
        int kept[8], c = 0;
#pragma unroll
        for (int j = 0; j < 8; ++j) {
            kept[j] = (mask[b * S_LEN + t0 + j] == 0);
            c += kept[j];
        }
        sc[tid] = c;
        __syncthreads();
        for (int off = 1; off < 256; off <<= 1) {
            int add = (tid >= off) ? sc[tid - off] : 0;
            __syncthreads();
            sc[tid] += add;
            __syncthreads();
        }
        int base = sc[tid] - c;
#pragma unroll
        for (int j = 0; j < 8; ++j)
            if (kept[j]) fwdmap[b * S_LEN + (base++)] = (short)(t0 + j);
        if (tid == 255) {
            cnt[b * 4 + 0] = sc[255];
            cnt[b * 4 + 1] = (sc[255] + 63) & ~63;
            cnt[b * 4 + 2] = (sc[255] + 127) & ~127;
            cnt[b * 4 + 3] = (sc[255] + 255) & ~255;
        }
    } else if (bx < 4 + TR_BLOCKS) {
        // ---- W transpose + cast ----
        float (*ts)[68] = (float(*)[68])smraw;
        const int idx = bx - 4;
        const int k0 = (idx & 15) * 64;
        const int n0 = ((idx >> 4) & 15) * 64;
        const int z  = idx >> 8;
        const float* Wsel = (z == 0) ? Wq : (z == 1) ? Wk : Wv;
        f16* outp = wt16 + (size_t)z * D_DIM * D_DIM;

        const int r  = tid >> 4;
        const int c4 = (tid & 15) * 4;
#pragma unroll
        for (int i = 0; i < 4; ++i) {
            f4 t = *(const f4*)&Wsel[(size_t)(k0 + r + i * 16) * D_DIM + n0 + c4];
            *(f4*)&ts[r + i * 16][c4] = t;
        }
        __syncthreads();
#pragma unroll
        for (int i = 0; i < 4; ++i) {
            int id2 = tid + i * 256;
            int nl = id2 >> 4;
            int k4 = (id2 & 15) * 4;
            f16x4 o;
#pragma unroll
            for (int j = 0; j < 4; ++j) o[j] = (f16)ts[k4 + j][nl];
            *(f16x4*)&outp[(size_t)(n0 + nl) * D_DIM + k0 + k4] = o;
        }
    } else {
        // ---- x -> f16 cast ----
        const size_t i = (size_t)(bx - 4 - TR_BLOCKS) * 256 + tid;
        f4 t = *(const f4*)&x[i * 4];
        f16x4 o;
        o[0] = (f16)t.x; o[1] = (f16)t.y; o[2] = (f16)t.z; o[3] = (f16)t.w;
        *(f16x4*)&x16[i * 4] = o;
    }
}

// ---------------------------------------------------------------------------
// QKV GEMM, f16 MFMA, BK=64, XOR-swizzled LDS (measured 0 bank conflicts).
// 2-phase double-buffer (round 5). Unchanged except Q scale: now
// 0.125*log2(e) so attn uses raw v_exp_f32 (2^x) with no per-element mul.
//   Q -> (B,H,S,W) * QSCALE ; K -> (B,H,jc,W) ; V -> (B,H,W,jc)
// ---------------------------------------------------------------------------
#define QSTAGE(BUF, K0) do {                                                    \
    _Pragma("unroll") for (int it_ = 0; it_ < 4; ++it_) {                       \
        int chunk_ = wid * 4 + it_;                                             \
        GLOAD_LDS16(&x16[(size_t)arows[it_] * D_DIM + (K0) + scw],              \
                    &As[BUF][chunk_ * 512]);                                    \
        GLOAD_LDS16(&Bg[(size_t)(chunk_ * 8 + srow) * D_DIM + (K0) + scw],      \
                    &Bs[BUF][chunk_ * 512]);                                    \
    } } while (0)

#define QCOMPUTE(BUF) do {                                                      \
    _Pragma("unroll") for (int kh_ = 0; kh_ < 2; ++kh_) {                       \
        const int csw_ = ((kh_ * 4 + quad) ^ (lx & 7)) * 8;                     \
        f16x8 af_[4], bf_[4];                                                   \
        _Pragma("unroll") for (int tm_ = 0; tm_ < 4; ++tm_)                     \
            af_[tm_] = *(const f16x8*)&As[BUF][(wm * 64 + tm_ * 16 + lx) * 64 + csw_]; \
        _Pragma("unroll") for (int tn_ = 0; tn_ < 4; ++tn_)                     \
            bf_[tn_] = *(const f16x8*)&Bs[BUF][(wn * 64 + tn_ * 16 + lx) * 64 + csw_]; \
        _Pragma("unroll") for (int tm_ = 0; tm_ < 4; ++tm_)                     \
        _Pragma("unroll") for (int tn_ = 0; tn_ < 4; ++tn_)                     \
            acc[tm_][tn_] = __builtin_amdgcn_mfma_f32_16x16x32_f16(             \
                af_[tm_], bf_[tn_], acc[tm_][tn_], 0, 0, 0);                    \
    } } while (0)

#define QVM0BAR() do {                                                          \
    asm volatile("s_waitcnt vmcnt(0)" ::: "memory");                            \
    __builtin_amdgcn_s_barrier();                                               \
    } while (0)

__global__ __launch_bounds__(256) void qkv_mfma_kernel(
    const f16* __restrict__ x16, const f16* __restrict__ wt16,
    const float* __restrict__ bq, const float* __restrict__ bk,
    const float* __restrict__ bv, const short* __restrict__ fwdmap,
    const int* __restrict__ cnt,
    f16* __restrict__ Qo, f16* __restrict__ Ko, f16* __restrict__ Vo)
{
    __shared__ f16 As[2][128 * 64];
    __shared__ f16 Bs[2][128 * 64];

    const int tid  = threadIdx.x;
    const int lane = tid & 63;
    const int wid  = tid >> 6;
    const int lx   = lane & 15;
    const int quad = lane >> 4;
    const int wm   = wid >> 1;
    const int wn   = wid & 1;

    const int r0    = blockIdx.y * 128;
    const int nt    = blockIdx.x;
    const int midx  = nt >> 3;
    const int c0    = (nt & 7) * 128;
    const int bB    = r0 >> 11;               // batch (tiles never straddle)
    const int r0loc = r0 & (S_LEN - 1);

    if (midx > 0 && r0loc >= cnt[bB * 4 + 2]) return;   // block-uniform exit

    const f16* Bg = wt16 + (size_t)midx * D_DIM * D_DIM + (size_t)c0 * D_DIM;

    const int srow = lane >> 3;               // 0..7 within 8-row chunk
    const int scw  = ((lane & 7) ^ srow) * 8; // swizzled source k-chunk

    // A-row (global, batch-absolute) for each of this wave's 4 chunks
    int arows[4];
#pragma unroll
    for (int it = 0; it < 4; ++it) {
        int rl = (wid * 4 + it) * 8 + srow;   // 0..127 within tile
        arows[it] = (midx == 0)
            ? (r0 + rl)
            : (bB * S_LEN + (int)fwdmap[bB * S_LEN + r0loc + rl]);
    }

    floatx4 acc[4][4];
#pragma unroll
    for (int a = 0; a < 4; ++a)
#pragma unroll
        for (int b = 0; b < 4; ++b) { acc[a][b][0]=0.f; acc[a][b][1]=0.f; acc[a][b][2]=0.f; acc[a][b][3]=0.f; }

    // prologue: stage tile 0, wait, sync
    QSTAGE(0, 0);
    QVM0BAR();

    // steady state: stage t+1 under compute t
#pragma unroll 2
    for (int t = 0; t < 14; t += 2) {
        QSTAGE(1, (t + 1) * 64);
        QCOMPUTE(0);
        QVM0BAR();
        QSTAGE(0, (t + 2) * 64);
        QCOMPUTE(1);
        QVM0BAR();
    }
    // tiles 14, 15
    QSTAGE(1, 15 * 64);
    QCOMPUTE(0);
    QVM0BAR();
    QCOMPUTE(1);

    const float* bp = (midx == 0) ? bq : (midx == 1) ? bk : bv;
    float bias[4];
#pragma unroll
    for (int tn = 0; tn < 4; ++tn)
        bias[tn] = bp[c0 + wn * 64 + tn * 16 + lx];

    if (midx == 0) {
#pragma unroll
        for (int tm = 0; tm < 4; ++tm) {
            int s = r0loc + wm * 64 + tm * 16 + quad * 4;
#pragma unroll
            for (int tn = 0; tn < 4; ++tn) {
                int gc = c0 + wn * 64 + tn * 16 + lx;
                int h = gc >> 6, w = gc & 63;
                size_t base = (((size_t)(bB * H_NUM + h)) * S_LEN + s) * W_DIM + w;
#pragma unroll
                for (int rr = 0; rr < 4; ++rr)
                    Qo[base + (size_t)rr * W_DIM] =
                        (f16)((acc[tm][tn][rr] + bias[tn]) * QSCALE);
            }
        }
    } else if (midx == 1) {
#pragma unroll
        for (int tm = 0; tm < 4; ++tm) {
            int jc = r0loc + wm * 64 + tm * 16 + quad * 4;
#pragma unroll
            for (int tn = 0; tn < 4; ++tn) {
                int gc = c0 + wn * 64 + tn * 16 + lx;
                int h = gc >> 6, w = gc & 63;
                size_t base = (((size_t)(bB * H_NUM + h)) * S_LEN + jc) * W_DIM + w;
#pragma unroll
                for (int rr = 0; rr < 4; ++rr)
                    Ko[base + (size_t)rr * W_DIM] = (f16)(acc[tm][tn][rr] + bias[tn]);
            }
        }
    } else {
#pragma unroll
        for (int tm = 0; tm < 4; ++tm) {
            int jc = r0loc + wm * 64 + tm * 16 + quad * 4;
#pragma unroll
            for (int tn = 0; tn < 4; ++tn) {
                int gc = c0 + wn * 64 + tn * 16 + lx;
                int h = gc >> 6, w = gc & 63;
                f16x4 v;
#pragma unroll
                for (int rr = 0; rr < 4; ++rr) v[rr] = (f16)(acc[tm][tn][rr] + bias[tn]);
                *(f16x4*)&Vo[(((size_t)(bB * H_NUM + h)) * W_DIM + w) * S_LEN + jc] = v;
            }
        }
    }
}

// ---------------------------------------------------------------------------
// Flash attention over COMPACTED keys, S^T formulation, 2 q-tiles per wave.
// ROUND 8: VALU-pipe reduction (round-7 counters: VALUBusy 46% vs MfmaUtil
// 21% -- softmax scalar chain is the critical pipe; staging/conflicts fixed
// and nulled). Three cuts in the softmax region:
//  * lsum via ones-row MFMA: o1[u] += mfma(ones8, P). The MFMA k-reduction
//    covers all 64 keys, so each lane ends with the FULL denominator for its
//    q -- removes 34 f32 adds/k-tile AND the final shfl_xor pair; costs 4
//    extra MFMA/k-tile on the idle matrix pipe. Denominator now sums the
//    same f16-rounded p's as the numerator (more self-consistent).
//  * v_cvt_pkrtz packed f32->f16 (16 instr instead of 32 scalar cvt).
//  * raw v_exp_f32 (FEXP2) with Q pre-scaled by 0.125*log2e: kills the
//    per-element mul. (Round-3's exp2f regression was OCML's fixup path +
//    barrier bug; this is the bare instruction.) exp2(-1e4) == 0 keeps the
//    masked tail exact.
// Staging (direct global_load_lds, double-buffer, source-side perm+swizzle)
// unchanged from round 7.
// ---------------------------------------------------------------------------
#define ASTAGE(BUF, K0) do {                                                    \
    _Pragma("unroll") for (int it_ = 0; it_ < 2; ++it_) {                       \
        int idx_ = tid + it_ * 256;                                             \
        int row_ = idx_ >> 3, ci_ = idx_ & 7;                                   \
        int sc_  = (ci_ ^ (row_ & 7)) * 8;                                      \
        int key_ = ((row_ >> 5) << 5) | (((row_ >> 2) & 3) << 3)                \
                 | (((row_ >> 4) & 1) << 2) | (row_ & 3);                       \
        GLOAD_LDS16(&Kg[(size_t)((K0) + key_) * W_DIM + sc_],                   \
                    (f16*)Ks[BUF] + idx_ * 8);                                  \
        GLOAD_LDS16(&Vg[(size_t)row_ * S_LEN + (K0) + sc_],                     \
                    (f16*)Vs[BUF] + idx_ * 8);                                  \
    } } while (0)

#define ACOMPUTE(BUF, K0) do {                                                  \
    const bool tail_ = ((K0) + 64 > count);                                     \
    u32x4 pbu[2][2];                                                            \
    _Pragma("unroll") for (int n = 0; n < 4; ++n) {                             \
        f16x8 ka0 = *(const f16x8*)&Ks[BUF][n * 16 + lx][((0 + quad) ^ swz) * 8]; \
        f16x8 ka1 = *(const f16x8*)&Ks[BUF][n * 16 + lx][((4 + quad) ^ swz) * 8]; \
        const int kb = (K0) + ((n >> 1) << 5) + (quad << 3) + ((n & 1) << 2);   \
        _Pragma("unroll") for (int u = 0; u < 2; ++u) {                         \
            floatx4 s; s[0]=0.f; s[1]=0.f; s[2]=0.f; s[3]=0.f;                  \
            s = __builtin_amdgcn_mfma_f32_16x16x32_f16(ka0, qb[u][0], s, 0, 0, 0); \
            s = __builtin_amdgcn_mfma_f32_16x16x32_f16(ka1, qb[u][1], s, 0, 0, 0); \
            float p[4];                                                         \
            if (tail_) {                                                        \
                _Pragma("unroll") for (int r = 0; r < 4; ++r)                   \
                    p[r] = FEXP2((kb + r < count) ? s[r] : -1.0e4f);            \
            } else {                                                            \
                _Pragma("unroll") for (int r = 0; r < 4; ++r)                   \
                    p[r] = FEXP2(s[r]);                                         \
            }                                                                   \
            auto t0_ = __builtin_amdgcn_cvt_pkrtz(p[0], p[1]);                  \
            auto t1_ = __builtin_amdgcn_cvt_pkrtz(p[2], p[3]);                  \
            pbu[u][n >> 1][(n & 1) * 2 + 0] = __builtin_bit_cast(u32, t0_);     \
            pbu[u][n >> 1][(n & 1) * 2 + 1] = __builtin_bit_cast(u32, t1_);     \
        }                                                                       \
    }                                                                           \
    _Pragma("unroll") for (int wb = 0; wb < 4; ++wb) {                          \
        _Pragma("unroll") for (int m = 0; m < 2; ++m) {                         \
            f16x8 va = *(const f16x8*)&Vs[BUF][wb * 16 + lx][((m * 4 + quad) ^ swz) * 8]; \
            _Pragma("unroll") for (int u = 0; u < 2; ++u)                       \
                o[u][wb] = __builtin_amdgcn_mfma_f32_16x16x32_f16(              \
                    va, __builtin_bit_cast(f16x8, pbu[u][m]), o[u][wb], 0, 0, 0); \
        }                                                                       \
    }                                                                           \
    _Pragma("unroll") for (int m = 0; m < 2; ++m)                               \
        _Pragma("unroll") for (int u = 0; u < 2; ++u)                           \
            o1[u] = __builtin_amdgcn_mfma_f32_16x16x32_f16(                     \
                ones8, __builtin_bit_cast(f16x8, pbu[u][m]), o1[u], 0, 0, 0);   \
    } while (0)

__global__ __launch_bounds__(256) void attn_kernel(
    const f16* __restrict__ Q, const f16* __restrict__ Kc,
    const f16* __restrict__ Vct, const int* __restrict__ cnt,
    float* __restrict__ out)
{
    __shared__ f16 Ks[2][64][64];   // [buf][perm key][k]  swizzled 16B chunks
    __shared__ f16 Vs[2][64][64];   // [buf][w][key]       swizzled 16B chunks

    const int tid  = threadIdx.x;
    const int lane = tid & 63;
    const int wid  = tid >> 6;
    const int lx   = lane & 15;
    const int quad = lane >> 4;
    const int qt = blockIdx.x, h = blockIdx.y, bb = blockIdx.z;

    const int count = cnt[bb * 4 + 0];
    const int scp   = cnt[bb * 4 + 1];
    const int ntile = scp >> 6;

    const size_t hoff = ((size_t)(bb * H_NUM + h)) * S_LEN * W_DIM;
    const f16* Qg = Q + hoff + (size_t)qt * 128 * W_DIM;
    const f16* Kg = Kc + hoff;
    const f16* Vg = Vct + hoff;

    f16x8 qb[2][2];
#pragma unroll
    for (int u = 0; u < 2; ++u) {
        int qrow = u * 64 + wid * 16 + lx;
        qb[u][0] = *(const f16x8*)&Qg[(size_t)qrow * W_DIM + quad * 8];
        qb[u][1] = *(const f16x8*)&Qg[(size_t)qrow * W_DIM + 32 + quad * 8];
    }

    const f16x8 ones8 = {(f16)1.f, (f16)1.f, (f16)1.f, (f16)1.f,
                         (f16)1.f, (f16)1.f, (f16)1.f, (f16)1.f};

    floatx4 o[2][4];
    floatx4 o1[2];
#pragma unroll
    for (int u = 0; u < 2; ++u) {
        o1[u][0]=0.f; o1[u][1]=0.f; o1[u][2]=0.f; o1[u][3]=0.f;
#pragma unroll
        for (int wb = 0; wb < 4; ++wb) { o[u][wb][0]=0.f; o[u][wb][1]=0.f; o[u][wb][2]=0.f; o[u][wb][3]=0.f; }
    }

    const int swz = lx & 7;                    // read-side de-swizzle key

    // prologue: stage tile 0, wait, sync
    ASTAGE(0, 0);
    asm volatile("s_waitcnt vmcnt(0)" ::: "memory");
    __builtin_amdgcn_s_barrier();

    // steady state: stage t+1 under compute t  (all guards block-uniform)
    for (int t = 0; t < ntile; t += 2) {
        if (t + 1 < ntile) ASTAGE(1, (t + 1) * 64);
        ACOMPUTE(0, t * 64);
        asm volatile("s_waitcnt vmcnt(0)" ::: "memory");
        __builtin_amdgcn_s_barrier();
        if (t + 1 < ntile) {
            if (t + 2 < ntile) ASTAGE(0, (t + 2) * 64);
            ACOMPUTE(1, (t + 1) * 64);
            asm volatile("s_waitcnt vmcnt(0)" ::: "memory");
            __builtin_amdgcn_s_barrier();
        }
    }

#pragma unroll
    for (int u = 0; u < 2; ++u) {
        // o1 rows are all identical key-sums (ones A-operand); element 0 is
        // this lane's full denominator for q = ... + lx. No cross-lane reduce.
        const float rl = 1.0f / o1[u][0];
        const int q = qt * 128 + u * 64 + wid * 16 + lx;
        const size_t base = ((size_t)bb * S_LEN + q) * D_DIM + h * W_DIM;
#pragma unroll
        for (int wb = 0; wb < 4; ++wb) {
            f4 r;
            r.x = o[u][wb][0] * rl;
            r.y = o[u][wb][1] * rl;
            r.z = o[u][wb][2] * rl;
            r.w = o[u][wb][3] * rl;
            *(f4*)&out[base + wb * 16 + quad * 4] = r;
        }
    }
}

// ---------------------------------------------------------------------------
extern "C" void kernel_launch(void* const* d_in, const int* in_sizes, int n_in,
                              void* d_out, int out_size, void* d_ws, size_t ws_size,
                              hipStream_t stream)
{
    const float* x    = (const float*)d_in[0];
    const float* Wq   = (const float*)d_in[1];
    const float* bq   = (const float*)d_in[2];
    const float* Wk   = (const float*)d_in[3];
    const float* bk   = (const float*)d_in[4];
    const float* Wv   = (const float*)d_in[5];
    const float* bv   = (const float*)d_in[6];
    const int*   mask = (const int*)d_in[7];
    float* out = (float*)d_out;

    const size_t per = (size_t)B_NUM * H_NUM * S_LEN * W_DIM;  // 8,388,608
    f16*   Q      = (f16*)d_ws;
    f16*   Kc     = Q + per;
    f16*   Vct    = Kc + per;
    f16*   x16    = Vct + per;
    f16*   wt16   = x16 + (size_t)(B_NUM * S_LEN) * D_DIM;
    int*   cnt    = (int*)(wt16 + (size_t)3 * D_DIM * D_DIM);
    short* fwdmap = (short*)(cnt + 4 * B_NUM);

    prep_kernel<<<4 + TR_BLOCKS + CAST_BLOCKS, 256, 0, stream>>>(
        mask, fwdmap, cnt, Wq, Wk, Wv, wt16, x, x16);
    qkv_mfma_kernel<<<dim3(24, 64), 256, 0, stream>>>(
        x16, wt16, bq, bk, bv, fwdmap, cnt, Q, Kc, Vct);
    attn_kernel<<<dim3(S_LEN / 128, H_NUM, B_NUM), 256, 0, stream>>>(
        Q, Kc, Vct, cnt, out);
}